// Round 10
// baseline (349.327 us; speedup 1.0000x reference)
//
#include <hip/hip_runtime.h>

#define D_FEAT 128
#define CAP 32
#define S1CAP (1 << 16)
#define LOGB 7
#define LOCB 128
#define BCAP 2560
#define CHUNK 4096
#define EPT 16
#define NBUK_MAX 1024
#define BPAD 8

typedef short bf16x8 __attribute__((ext_vector_type(8)));
typedef float f32x4 __attribute__((ext_vector_type(4)));

__device__ __forceinline__ unsigned short f2bf(float f) {
    unsigned u = __builtin_bit_cast(unsigned, f);
    u += 0x7FFF + ((u >> 16) & 1);   // round-to-nearest-even
    return (unsigned short)(u >> 16);
}

// ws int layout: [flag:64][s1cnt:64][spill1:2*S1CAP][bincnt:NBUK_MAX*BPAD]
// [bins:NBUK*BCAP] then Wc[128*256] bf16, xb[N*64] uint (bf16x2)

// ---------------- K0: tiny prep: detect i64 + zero counters (8 blocks) ----------
__global__ __launch_bounds__(256) void tprep_kernel(
    const int* __restrict__ ei, int* __restrict__ flag, int* __restrict__ s1cnt,
    int* __restrict__ bincnt) {
    const int b = blockIdx.x;
    const int t = threadIdx.x;
    for (int i = b * 256 + t; i < NBUK_MAX * BPAD; i += 8 * 256) bincnt[i] = 0;
    if (b == 0) {
        __shared__ int nzs[4];
        int nz = 0;
        for (int i = t; i < 4096; i += 256) nz |= (ei[2 * i + 1] != 0);
        unsigned long long bal = __ballot(nz);
        if ((t & 63) == 0) nzs[t >> 6] = (bal != 0ull) ? 1 : 0;
        __syncthreads();
        if (t == 0) {
            *flag = (nzs[0] | nzs[1] | nzs[2] | nzs[3]) ? 0 : 1;  // 1 = int64 input
            *s1cnt = 0;
        }
    }
}

// ---------------- K1: merged bin + Wc pack + x->bf16 (one launch) ----------------
// Bin blocks stage their EPT=16 edges/thread in REGISTERS (LDS only 8KB for
// hist+rbase) so the streaming xb blocks in the same kernel keep full
// occupancy. Single edge read per edge.
__global__ __launch_bounds__(256) void bwx_kernel(
    const int* __restrict__ ei, const int* __restrict__ flag,
    int* __restrict__ bincnt, unsigned* __restrict__ bins,
    int* __restrict__ s1cnt, int* __restrict__ spill1, int E, int N, int NBUK,
    int BINB,
    const float* __restrict__ Wl, const float* __restrict__ Wr,
    unsigned short* __restrict__ Wc,
    const float4* __restrict__ x4, uint2* __restrict__ xb2, long total4) {
    const int b = blockIdx.x;
    const int t = threadIdx.x;

    if (b < BINB) {
        __shared__ int hist[NBUK_MAX];
        __shared__ int rbase[NBUK_MAX];
        unsigned ent[EPT];
        int ebk[EPT];
        const long e0 = (long)b * CHUNK;
        const int cnt = (int)min((long)CHUNK, (long)E - e0);
        const int is64 = *flag;

        for (int i = t; i < NBUK; i += 256) hist[i] = 0;
        __syncthreads();

        // phase A: read edges ONCE into registers; histogram buckets
#pragma unroll
        for (int k = 0; k < EPT; ++k) {
            int i = k * 256 + t;
            if (i < cnt) {
                long e = e0 + i;
                int src, dst;
                if (is64) {
                    src = (int)((const long long*)ei)[e];
                    dst = (int)((const long long*)ei)[(long)E + e];
                } else {
                    src = ei[e];
                    dst = ei[(long)E + e];
                }
                src = min(max(src, 0), N - 1);
                dst = min(max(dst, 0), N - 1);
                int bk = dst >> LOGB;
                ent[k] = ((unsigned)(dst & (LOCB - 1)) << 25) | (unsigned)src;
                ebk[k] = bk;
                atomicAdd(&hist[bk], 1);
            } else {
                ebk[k] = -1;
            }
        }
        __syncthreads();

        // phase B: reserve contiguous ranges (padded global counters)
        for (int i = t; i < NBUK; i += 256) {
            int h = hist[i];
            rbase[i] = (h > 0) ? atomicAdd(&bincnt[i * BPAD], h) : 0;
            hist[i] = 0;  // reuse as bump counter
        }
        __syncthreads();

        // phase C: scatter from registers
#pragma unroll
        for (int k = 0; k < EPT; ++k) {
            int bk = ebk[k];
            if (bk >= 0) {
                int slot = rbase[bk] + atomicAdd(&hist[bk], 1);
                if (slot < BCAP) {
                    bins[(long)bk * BCAP + slot] = ent[k];
                } else {
                    unsigned v = ent[k];
                    int sp = atomicAdd(s1cnt, 1);
                    if (sp < S1CAP) {
                        spill1[2 * sp] = (int)(v & 0x1FFFFFFu);
                        spill1[2 * sp + 1] = (bk << LOGB) | (int)(v >> 25);
                    }
                }
            }
        }
    } else if (b < BINB + 128) {
        int n = b - BINB;  // 0..127
        float w = (t < 128) ? Wl[n * 128 + t] : Wr[n * 128 + (t - 128)];
        Wc[n * 256 + t] = f2bf(w);
    } else {
        long gid = (long)(b - BINB - 128) * 256 + t;
        if (gid < total4) {
            float4 v = x4[gid];
            uint2 o;
            o.x = (unsigned)f2bf(v.x) | ((unsigned)f2bf(v.y) << 16);
            o.y = (unsigned)f2bf(v.z) | ((unsigned)f2bf(v.w) << 16);
            xb2[gid] = o;
        }
    }
}

__device__ __forceinline__ void acc_row(float* acc, uint4 v) {
    acc[0] += __builtin_bit_cast(float, v.x << 16);
    acc[1] += __builtin_bit_cast(float, v.x & 0xFFFF0000u);
    acc[2] += __builtin_bit_cast(float, v.y << 16);
    acc[3] += __builtin_bit_cast(float, v.y & 0xFFFF0000u);
    acc[4] += __builtin_bit_cast(float, v.z << 16);
    acc[5] += __builtin_bit_cast(float, v.z & 0xFFFF0000u);
    acc[6] += __builtin_bit_cast(float, v.w << 16);
    acc[7] += __builtin_bit_cast(float, v.w & 0xFFFF0000u);
}

// ---------------- K2: fused scan + gather + MFMA GEMM --------------------------
// 8 sub-blocks (16 nodes each) per 128-node bucket; g = bid % STRIDE,
// j = bid / STRIDE with STRIDE % 8 == 0 puts all 8 sub-blocks of a bucket on
// ONE XCD -> the bucket's bins slice is L2-resident after the first read.
// Block scans bucket entries once (8/thread), builds the 16-node adj image +
// degrees in LDS, then quad-per-node gather from the LDS image (no global
// adj array at all). deg>CAP nodes take an exact serial rescan path.
__global__ __launch_bounds__(256) void gg_kernel(
    const unsigned int* __restrict__ xb, const unsigned* __restrict__ bins,
    const int* __restrict__ bincnt, const int* __restrict__ s1cnt,
    const int* __restrict__ spill1, const unsigned short* __restrict__ Wc,
    const float* __restrict__ bl, float* __restrict__ out, int N, int STRIDE,
    int NBUK) {
    __shared__ __align__(16) unsigned short A[16 * 264];
    __shared__ int cnt16[16];
    __shared__ int adjimg[16 * CAP];

    const int g = blockIdx.x % STRIDE;  // bucket
    const int j = blockIdx.x / STRIDE;  // 16-node sub-range within bucket
    if (g >= NBUK) return;
    const int t = threadIdx.x;
    const int wv = t >> 6;
    const int lane = t & 63;
    const int fq = lane & 15;   // position within quad
    const int qd = lane >> 4;   // quad id = which of the wave's 4 nodes
    const int n0 = g * LOCB + j * 16;
    const int ldb = j * 16;     // local-id base within bucket

    if (t < 16) cnt16[t] = 0;
    __syncthreads();

    // scan bucket entries; keep only this block's 16 nodes
    const int cntE = min(bincnt[g * BPAD], BCAP);
    for (int i = t; i < cntE; i += 256) {
        unsigned v = bins[(long)g * BCAP + i];
        unsigned d = (v >> 25) - (unsigned)ldb;
        if (d < 16u) {
            int slot = atomicAdd(&cnt16[d], 1);
            if (slot < CAP) adjimg[d * CAP + slot] = (int)(v & 0x1FFFFFFu);
        }
    }
    // bucket-overflow entries (normally zero)
    const int sc = min(*s1cnt, S1CAP);
    for (int i = t; i < sc; i += 256) {
        unsigned d = (unsigned)(spill1[2 * i + 1] - n0);
        if (d < 16u) {
            int slot = atomicAdd(&cnt16[d], 1);
            if (slot < CAP) adjimg[d * CAP + slot] = spill1[2 * i];
        }
    }

    // own rows (independent loads, overlap the scan's tail)
    unsigned xv[4];
#pragma unroll
    for (int q = 0; q < 4; ++q) {
        int nn = n0 + wv * 4 + q;
        xv[q] = (nn < N) ? xb[(long)nn * 64 + lane] : 0u;
    }
    __syncthreads();

    const int r = wv * 4 + qd;
    const int n = n0 + r;
    const int deg = cnt16[r];
    float acc[8] = {0.f, 0.f, 0.f, 0.f, 0.f, 0.f, 0.f, 0.f};

    if (deg > 0 && n < N) {
        if (deg <= CAP) {
            const int cq = deg;
            const int mx = (cq + 3) & ~3;
            uint4 va[4], vb[4];
#pragma unroll
            for (int k = 0; k < 4; ++k) {
                int s = adjimg[r * CAP + min(k, cq - 1)];
                va[k] = *(const uint4*)&xb[(long)s * 64 + fq * 4];
            }
            for (int base = 0; base < mx; base += 4) {
#pragma unroll
                for (int k = 0; k < 4; ++k) {
                    int s = adjimg[r * CAP + min(base + 4 + k, cq - 1)];
                    vb[k] = *(const uint4*)&xb[(long)s * 64 + fq * 4];
                }
#pragma unroll
                for (int k = 0; k < 4; ++k) {
                    if (base + k < cq) acc_row(acc, va[k]);
                }
#pragma unroll
                for (int k = 0; k < 4; ++k) va[k] = vb[k];
            }
        } else {
            // exact rare path: rescan every entry for this node
            const int myld = ldb + r;
            for (int e = 0; e < cntE; ++e) {
                unsigned v = bins[(long)g * BCAP + e];
                if ((int)(v >> 25) == myld) {
                    int s = (int)(v & 0x1FFFFFFu);
                    acc_row(acc, *(const uint4*)&xb[(long)s * 64 + fq * 4]);
                }
            }
            for (int i = 0; i < sc; ++i) {
                if (spill1[2 * i + 1] == n) {
                    int s = spill1[2 * i];
                    acc_row(acc, *(const uint4*)&xb[(long)s * 64 + fq * 4]);
                }
            }
        }
    }

    const float iv = 1.0f / (float)max(deg, 1);
    uint4 o;
    o.x = (unsigned)f2bf(acc[0] * iv) | ((unsigned)f2bf(acc[1] * iv) << 16);
    o.y = (unsigned)f2bf(acc[2] * iv) | ((unsigned)f2bf(acc[3] * iv) << 16);
    o.z = (unsigned)f2bf(acc[4] * iv) | ((unsigned)f2bf(acc[5] * iv) << 16);
    o.w = (unsigned)f2bf(acc[6] * iv) | ((unsigned)f2bf(acc[7] * iv) << 16);
    *(uint4*)&A[r * 264 + fq * 8] = o;
#pragma unroll
    for (int q = 0; q < 4; ++q)
        *(unsigned*)&A[(wv * 4 + q) * 264 + 128 + 2 * lane] = xv[q];
    __syncthreads();

    // phase 2: MFMA — wave w computes cols [w*32, w*32+32)
    const int l15 = lane & 15;
    const int quad = lane >> 4;
    f32x4 acc2[2];
    acc2[0] = (f32x4){0.f, 0.f, 0.f, 0.f};
    acc2[1] = (f32x4){0.f, 0.f, 0.f, 0.f};

#pragma unroll
    for (int kc = 0; kc < 8; ++kc) {
        const int k0 = kc * 32;
        bf16x8 af = *(const bf16x8*)&A[l15 * 264 + k0 + quad * 8];
#pragma unroll
        for (int nt = 0; nt < 2; ++nt) {
            int col = wv * 32 + nt * 16 + l15;
            bf16x8 bf = *(const bf16x8*)&Wc[col * 256 + k0 + quad * 8];
            acc2[nt] = __builtin_amdgcn_mfma_f32_16x16x32_bf16(af, bf, acc2[nt], 0, 0, 0);
        }
    }

    // epilogue: C/D layout col=lane&15, row=quad*4+reg
#pragma unroll
    for (int nt = 0; nt < 2; ++nt) {
        int col = wv * 32 + nt * 16 + l15;
        float bias = bl[col];
#pragma unroll
        for (int rr = 0; rr < 4; ++rr) {
            int node = n0 + quad * 4 + rr;
            if (node < N) out[(long)node * 128 + col] = acc2[nt][rr] + bias;
        }
    }
}

extern "C" void kernel_launch(void* const* d_in, const int* in_sizes, int n_in,
                              void* d_out, int out_size, void* d_ws, size_t ws_size,
                              hipStream_t stream) {
    const float* x = (const float*)d_in[0];
    const int* ei = (const int*)d_in[1];
    const float* Wl = (const float*)d_in[2];
    const float* bl = (const float*)d_in[3];
    const float* Wr = (const float*)d_in[4];
    float* out = (float*)d_out;

    const int N = in_sizes[0] / D_FEAT;  // 100000
    const int E = in_sizes[1] / 2;       // 1600000
    const int NBUK = (N + LOCB - 1) >> LOGB;   // 782 (<= NBUK_MAX)
    const int BINB = (E + CHUNK - 1) / CHUNK;  // 391
    const int STRIDE = (NBUK + 7) & ~7;        // 784 (mult of 8 -> XCD locality)

    int* wsI = (int*)d_ws;
    int* flag = wsI;                          // 64
    int* s1cnt = flag + 64;                   // 64
    int* spill1 = s1cnt + 64;                 // 2*S1CAP
    int* bincnt = spill1 + 2 * S1CAP;         // NBUK_MAX*BPAD
    unsigned* bins = (unsigned*)(bincnt + NBUK_MAX * BPAD);       // NBUK*BCAP
    unsigned short* Wc = (unsigned short*)(bins + (long)NBUK * BCAP);  // 64KB
    unsigned int* xb = (unsigned int*)(Wc + 128 * 256);           // N*64 uints

    const long total4 = (long)N * 32;
    const int XBB = (int)((total4 + 255) / 256);

    tprep_kernel<<<8, 256, 0, stream>>>(ei, flag, s1cnt, bincnt);
    bwx_kernel<<<BINB + 128 + XBB, 256, 0, stream>>>(
        ei, flag, bincnt, bins, s1cnt, spill1, E, N, NBUK, BINB, Wl, Wr, Wc,
        (const float4*)x, (uint2*)xb, total4);
    gg_kernel<<<8 * STRIDE, 256, 0, stream>>>(xb, bins, bincnt, s1cnt, spill1, Wc,
                                              bl, out, N, STRIDE, NBUK);
}

// Round 11
// 248.807 us; speedup vs baseline: 1.4040x; 1.4040x over previous
//
#include <hip/hip_runtime.h>

#define D_FEAT 128
#define CAP 32
#define S2CAP (1 << 16)
#define LOGB 7
#define LOCB 128
#define CHUNK 4096
#define EPT 16
#define NBUK_MAX 1024
#define OSTR 1032

typedef short bf16x8 __attribute__((ext_vector_type(8)));
typedef float f32x4 __attribute__((ext_vector_type(4)));

__device__ __forceinline__ unsigned short f2bf(float f) {
    unsigned u = __builtin_bit_cast(unsigned, f);
    u += 0x7FFF + ((u >> 16) & 1);   // round-to-nearest-even
    return (unsigned short)(u >> 16);
}

// ws int layout: [flag:64][s2cnt:64][spill2:2*S2CAP][cursor:N]
// [offs2: NCHUNK*OSTR u16][bins2: NCHUNK*CHUNK u32][adj:N*CAP]
// then Wc[128*256] bf16, xb[N*64] uint (bf16x2)

// ---------------- K0: tiny prep: detect i64 + zero s2cnt (1 block) ----------
__global__ __launch_bounds__(256) void tprep_kernel(
    const int* __restrict__ ei, int* __restrict__ flag, int* __restrict__ s2cnt) {
    const int t = threadIdx.x;
    __shared__ int nzs[4];
    int nz = 0;
    for (int i = t; i < 4096; i += 256) nz |= (ei[2 * i + 1] != 0);
    unsigned long long bal = __ballot(nz);
    if ((t & 63) == 0) nzs[t >> 6] = (bal != 0ull) ? 1 : 0;
    __syncthreads();
    if (t == 0) {
        *flag = (nzs[0] | nzs[1] | nzs[2] | nzs[3]) ? 0 : 1;  // 1 = int64 input
        *s2cnt = 0;
    }
}

// ---------------- K1: merged atomic-free bin-sort + Wc pack + x->bf16 -----------
// Bin blocks bucket-sort their own CHUNK=4096 edges entirely in LDS:
//   A: edges -> regs, LDS histogram
//   B: LDS exclusive scan over buckets (replaces global atomic reserve),
//      write per-block u16 offset row
//   C: LDS bump-scatter into sorted buffer
//   D: coalesced uint4 stream-out into the block's OWN fixed region
// No global atomics anywhere; overflow is impossible (chunk fits region).
__global__ __launch_bounds__(256) void bwx_kernel(
    const int* __restrict__ ei, const int* __restrict__ flag,
    unsigned short* __restrict__ offs2, unsigned* __restrict__ bins2,
    int E, int N, int NBUK, int BINB,
    const float* __restrict__ Wl, const float* __restrict__ Wr,
    unsigned short* __restrict__ Wc,
    const float4* __restrict__ x4, uint2* __restrict__ xb2, long total4) {
    __shared__ int hist[NBUK_MAX + 8];
    __shared__ int wsum[256];
    __shared__ unsigned sorted[CHUNK];
    const int b = blockIdx.x;
    const int t = threadIdx.x;

    if (b < BINB) {
        const long e0 = (long)b * CHUNK;
        const int cnt = (int)min((long)CHUNK, (long)E - e0);
        const int is64 = *flag;

        for (int i = t; i < NBUK_MAX + 8; i += 256) hist[i] = 0;
        __syncthreads();

        // A: read edges once into registers; histogram buckets
        unsigned ent[EPT];
        int ebk[EPT];
#pragma unroll
        for (int k = 0; k < EPT; ++k) {
            int i = k * 256 + t;
            if (i < cnt) {
                long e = e0 + i;
                int src, dst;
                if (is64) {
                    src = (int)((const long long*)ei)[e];
                    dst = (int)((const long long*)ei)[(long)E + e];
                } else {
                    src = ei[e];
                    dst = ei[(long)E + e];
                }
                src = min(max(src, 0), N - 1);
                dst = min(max(dst, 0), N - 1);
                int bk = dst >> LOGB;
                ent[k] = ((unsigned)(dst & (LOCB - 1)) << 25) | (unsigned)src;
                ebk[k] = bk;
                atomicAdd(&hist[bk], 1);
            } else {
                ebk[k] = -1;
            }
        }
        __syncthreads();

        // B: exclusive scan over 1024 bucket counts (4 per thread + block scan)
        int v0 = hist[4 * t], v1 = hist[4 * t + 1], v2 = hist[4 * t + 2],
            v3 = hist[4 * t + 3];
        int s = v0 + v1 + v2 + v3;
        wsum[t] = s;
        __syncthreads();
        for (int off = 1; off < 256; off <<= 1) {
            int a = (t >= off) ? wsum[t - off] : 0;
            __syncthreads();
            wsum[t] += a;
            __syncthreads();
        }
        int base = wsum[t] - s;  // exclusive
        hist[4 * t] = base;
        hist[4 * t + 1] = base + v0;
        hist[4 * t + 2] = base + v0 + v1;
        hist[4 * t + 3] = base + v0 + v1 + v2;
        __syncthreads();
        // write offset row (u16), entries [0, NBUK] inclusive
        unsigned short* orow = offs2 + (long)b * OSTR;
        for (int i = t; i <= NBUK; i += 256) orow[i] = (unsigned short)hist[i];
        __syncthreads();

        // C: bump-scatter into sorted LDS buffer
#pragma unroll
        for (int k = 0; k < EPT; ++k) {
            if (ebk[k] >= 0) {
                int slot = atomicAdd(&hist[ebk[k]], 1);
                sorted[slot] = ent[k];
            }
        }
        __syncthreads();

        // D: coalesced stream-out (full region; garbage beyond cnt never read)
        uint4* dstp = (uint4*)(bins2 + (long)b * CHUNK);
        const uint4* srcp = (const uint4*)sorted;
#pragma unroll
        for (int k = 0; k < CHUNK / 4 / 256; ++k) dstp[k * 256 + t] = srcp[k * 256 + t];
    } else if (b < BINB + 128) {
        int n = b - BINB;  // 0..127
        float w = (t < 128) ? Wl[n * 128 + t] : Wr[n * 128 + (t - 128)];
        Wc[n * 256 + t] = f2bf(w);
    } else {
        long gid = (long)(b - BINB - 128) * 256 + t;
        if (gid < total4) {
            float4 v = x4[gid];
            uint2 o;
            o.x = (unsigned)f2bf(v.x) | ((unsigned)f2bf(v.y) << 16);
            o.y = (unsigned)f2bf(v.z) | ((unsigned)f2bf(v.w) << 16);
            xb2[gid] = o;
        }
    }
}

// ---------------- K2: per-bucket CSR fill from per-block slices ------------------
// Bucket bk gathers its slice from each of NCHUNK block regions (offset table),
// builds the 128-node adj image in LDS, coalesced writeout + cursor.
__global__ __launch_bounds__(256) void fill2_kernel(
    const unsigned* __restrict__ bins2, const unsigned short* __restrict__ offs2,
    int* __restrict__ adj, int* __restrict__ cursor,
    int* __restrict__ s2cnt, int* __restrict__ spill2, int N, int NCHUNK) {
    __shared__ int cur[LOCB];
    __shared__ __align__(16) int adjimg[LOCB * CAP];  // 16KB bucket adj image
    const int bk = blockIdx.x;
    const int t = threadIdx.x;
    if (t < LOCB) cur[t] = 0;
    __syncthreads();
    const int nb = bk << LOGB;
    for (int b = t; b < NCHUNK; b += 256) {
        const unsigned short* orow = offs2 + (long)b * OSTR;
        int o0 = orow[bk];
        int o1 = orow[bk + 1];
        const unsigned* reg = bins2 + (long)b * CHUNK;
        for (int k = o0; k < o1; ++k) {
            unsigned v = reg[k];
            int ld = (int)(v >> 25);
            int slot = atomicAdd(&cur[ld], 1);
            if (slot < CAP) {
                adjimg[ld * CAP + slot] = (int)(v & 0x1FFFFFFu);
            } else {
                int sp = atomicAdd(s2cnt, 1);
                if (sp < S2CAP) {
                    spill2[2 * sp] = (int)(v & 0x1FFFFFFu);
                    spill2[2 * sp + 1] = nb + ld;
                }
            }
        }
    }
    __syncthreads();
    // coalesced writeout: bucket's adj slice is contiguous (node-major*CAP)
    const int lim = min(LOCB, N - nb);
    const int nvec = lim * CAP / 4;
    uint4* dstp = (uint4*)&adj[(long)nb * CAP];
    const uint4* srcp = (const uint4*)adjimg;
    for (int i = t; i < nvec; i += 256) dstp[i] = srcp[i];
    if (t < LOCB && nb + t < N) cursor[nb + t] = cur[t];
}

__device__ __forceinline__ void acc_row(float* acc, uint4 v) {
    acc[0] += __builtin_bit_cast(float, v.x << 16);
    acc[1] += __builtin_bit_cast(float, v.x & 0xFFFF0000u);
    acc[2] += __builtin_bit_cast(float, v.y << 16);
    acc[3] += __builtin_bit_cast(float, v.y & 0xFFFF0000u);
    acc[4] += __builtin_bit_cast(float, v.z << 16);
    acc[5] += __builtin_bit_cast(float, v.z & 0xFFFF0000u);
    acc[6] += __builtin_bit_cast(float, v.w << 16);
    acc[7] += __builtin_bit_cast(float, v.w & 0xFFFF0000u);
}

// src for edge e of this quad's node; e >= cq redirects to row 0 (L1-hot).
__device__ __forceinline__ int pick_src(int adjv, int adjv2, int e, int cq, int qd) {
    int ec = e & 31;
    int s = __shfl((ec < 16) ? adjv : adjv2, qd * 16 + (ec & 15));
    return (e < cq) ? s : 0;
}

// ---------------- K3: fused gather + MFMA GEMM, 16 nodes per block ----------------
__global__ __launch_bounds__(256) void gg_kernel(
    const unsigned int* __restrict__ xb, const int* __restrict__ cursor,
    const int* __restrict__ adj, const unsigned short* __restrict__ Wc,
    const float* __restrict__ bl, float* __restrict__ out, int N) {
    __shared__ __align__(16) unsigned short A[16 * 264];

    const int t = threadIdx.x;
    const int wv = t >> 6;
    const int lane = t & 63;
    const int n0 = blockIdx.x * 16;
    const int fq = lane & 15;   // position within quad
    const int qd = lane >> 4;   // quad id = which of the wave's 4 nodes

    const int n = n0 + wv * 4 + qd;
    const int nc = min(n, N - 1);

    // independent front-loads: degree, adjacency (2x), own rows (4x)
    const int deg = (n < N) ? cursor[n] : 0;
    int adjv = adj[(long)nc * CAP + fq];
    int adjv2 = adj[(long)nc * CAP + 16 + fq];

    unsigned xv[4];
#pragma unroll
    for (int q = 0; q < 4; ++q) {
        int nn = n0 + wv * 4 + q;
        xv[q] = (nn < N) ? xb[(long)nn * 64 + lane] : 0u;
    }

    // clamp stored srcs (entries beyond deg are uninitialized garbage)
    adjv = min(max(adjv, 0), N - 1);
    adjv2 = min(max(adjv2, 0), N - 1);

    const int cq = min(deg, CAP);
    int mx = max(cq, __shfl_xor(cq, 16));
    mx = max(mx, __shfl_xor(mx, 32));
    mx = (mx + 3) & ~3;  // pad to chunk of 4

    float acc[8] = {0.f, 0.f, 0.f, 0.f, 0.f, 0.f, 0.f, 0.f};
    uint4 va[4], vb[4];
    // prefetch chunk 0
#pragma unroll
    for (int j = 0; j < 4; ++j) {
        int s = pick_src(adjv, adjv2, j, cq, qd);
        va[j] = *(const uint4*)&xb[(long)s * 64 + fq * 4];
    }
    for (int base = 0; base < mx; base += 4) {
        // issue next chunk's 4 loads before consuming current chunk
#pragma unroll
        for (int j = 0; j < 4; ++j) {
            int s = pick_src(adjv, adjv2, base + 4 + j, cq, qd);
            vb[j] = *(const uint4*)&xb[(long)s * 64 + fq * 4];
        }
#pragma unroll
        for (int j = 0; j < 4; ++j) {
            if (base + j < cq) acc_row(acc, va[j]);
        }
#pragma unroll
        for (int j = 0; j < 4; ++j) va[j] = vb[j];
    }

    const float iv = 1.0f / (float)max(deg, 1);
    uint4 o;
    o.x = (unsigned)f2bf(acc[0] * iv) | ((unsigned)f2bf(acc[1] * iv) << 16);
    o.y = (unsigned)f2bf(acc[2] * iv) | ((unsigned)f2bf(acc[3] * iv) << 16);
    o.z = (unsigned)f2bf(acc[4] * iv) | ((unsigned)f2bf(acc[5] * iv) << 16);
    o.w = (unsigned)f2bf(acc[6] * iv) | ((unsigned)f2bf(acc[7] * iv) << 16);
    *(uint4*)&A[(wv * 4 + qd) * 264 + fq * 8] = o;
#pragma unroll
    for (int q = 0; q < 4; ++q)
        *(unsigned*)&A[(wv * 4 + q) * 264 + 128 + 2 * lane] = xv[q];
    __syncthreads();

    // phase 2: MFMA — wave w computes cols [w*32, w*32+32)
    const int l15 = lane & 15;
    const int quad = lane >> 4;
    f32x4 acc2[2];
    acc2[0] = (f32x4){0.f, 0.f, 0.f, 0.f};
    acc2[1] = (f32x4){0.f, 0.f, 0.f, 0.f};

#pragma unroll
    for (int kc = 0; kc < 8; ++kc) {
        const int k0 = kc * 32;
        bf16x8 af = *(const bf16x8*)&A[l15 * 264 + k0 + quad * 8];
#pragma unroll
        for (int nt = 0; nt < 2; ++nt) {
            int col = wv * 32 + nt * 16 + l15;
            bf16x8 bf = *(const bf16x8*)&Wc[col * 256 + k0 + quad * 8];
            acc2[nt] = __builtin_amdgcn_mfma_f32_16x16x32_bf16(af, bf, acc2[nt], 0, 0, 0);
        }
    }

    // epilogue: C/D layout col=lane&15, row=quad*4+reg
#pragma unroll
    for (int nt = 0; nt < 2; ++nt) {
        int col = wv * 32 + nt * 16 + l15;
        float bias = bl[col];
#pragma unroll
        for (int r = 0; r < 4; ++r) {
            int node = n0 + quad * 4 + r;
            if (node < N) out[(long)node * 128 + col] = acc2[nt][r] + bias;
        }
    }
}

// ---------------- K4: exact CAP-overflow fixup (normally ~0 iterations) ----------
__global__ __launch_bounds__(256) void spill2_kernel(
    const float* __restrict__ x, const float* __restrict__ Wl,
    const int* __restrict__ cursor, const int* __restrict__ s2cnt,
    const int* __restrict__ spill2, float* __restrict__ out) {
    const int wv = threadIdx.x >> 6;
    const int lane = threadIdx.x & 63;
    const int sc = min(*s2cnt, S2CAP);
    for (int i = blockIdx.x * 4 + wv; i < sc; i += gridDim.x * 4) {
        int src = spill2[2 * i];
        int dst = spill2[2 * i + 1];
        float inv = 1.0f / (float)max(cursor[dst], 1);
#pragma unroll
        for (int cc = 0; cc < 2; ++cc) {
            int c = lane + cc * 64;
            float s = 0.0f;
            for (int k = 0; k < 128; k += 4) {
                float4 w4 = *(const float4*)&Wl[c * 128 + k];
                float4 x4 = *(const float4*)&x[(long)src * 128 + k];
                s += w4.x * x4.x + w4.y * x4.y + w4.z * x4.z + w4.w * x4.w;
            }
            atomicAdd(&out[(long)dst * 128 + c], s * inv);
        }
    }
}

extern "C" void kernel_launch(void* const* d_in, const int* in_sizes, int n_in,
                              void* d_out, int out_size, void* d_ws, size_t ws_size,
                              hipStream_t stream) {
    const float* x = (const float*)d_in[0];
    const int* ei = (const int*)d_in[1];
    const float* Wl = (const float*)d_in[2];
    const float* bl = (const float*)d_in[3];
    const float* Wr = (const float*)d_in[4];
    float* out = (float*)d_out;

    const int N = in_sizes[0] / D_FEAT;  // 100000
    const int E = in_sizes[1] / 2;       // 1600000
    const int NBUK = (N + LOCB - 1) >> LOGB;     // 782 (<= NBUK_MAX)
    const int NCHUNK = (E + CHUNK - 1) / CHUNK;  // 391

    int* wsI = (int*)d_ws;
    int* flag = wsI;                          // 64
    int* s2cnt = flag + 64;                   // 64
    int* spill2 = s2cnt + 64;                 // 2*S2CAP
    int* cursor = spill2 + 2 * S2CAP;         // N
    unsigned short* offs2 = (unsigned short*)(cursor + N);        // NCHUNK*OSTR u16
    unsigned* bins2 = (unsigned*)(offs2 + (long)NCHUNK * OSTR + 64);  // NCHUNK*CHUNK
    int* adj = (int*)(bins2 + (long)NCHUNK * CHUNK);              // N*CAP
    unsigned short* Wc = (unsigned short*)(adj + (long)N * CAP);  // 64KB
    unsigned int* xb = (unsigned int*)(Wc + 128 * 256);           // N*64 uints

    const long total4 = (long)N * 32;
    const int XBB = (int)((total4 + 255) / 256);

    tprep_kernel<<<1, 256, 0, stream>>>(ei, flag, s2cnt);
    bwx_kernel<<<NCHUNK + 128 + XBB, 256, 0, stream>>>(
        ei, flag, offs2, bins2, E, N, NBUK, NCHUNK, Wl, Wr, Wc,
        (const float4*)x, (uint2*)xb, total4);
    fill2_kernel<<<NBUK, 256, 0, stream>>>(bins2, offs2, adj, cursor, s2cnt, spill2,
                                           N, NCHUNK);
    gg_kernel<<<(N + 15) / 16, 256, 0, stream>>>(xb, cursor, adj, Wc, bl, out, N);
    spill2_kernel<<<64, 256, 0, stream>>>(x, Wl, cursor, s2cnt, spill2, out);
}